// Round 3
// baseline (862.643 us; speedup 1.0000x reference)
//
#include <hip/hip_runtime.h>
#include <hip/hip_bf16.h>

#define N 1024
#define E 128
#define NEG 0.2f
#define AST 136  // padded LDS stride (shorts) for B tile
#define JB 8    // j values per block in main_gemm

typedef __attribute__((ext_vector_type(8))) short short8;
typedef __attribute__((ext_vector_type(4))) float float4v;

__device__ __forceinline__ short f2bf(float x){
  unsigned u = __float_as_uint(x);
  u += 0x7fffu + ((u >> 16) & 1u);   // round-to-nearest-even
  return (short)(u >> 16);
}

__device__ __forceinline__ short8 cvt2(float4 a, float4 b){
  short8 r;
  r[0] = f2bf(a.x); r[1] = f2bf(a.y); r[2] = f2bf(a.z); r[3] = f2bf(a.w);
  r[4] = f2bf(b.x); r[5] = f2bf(b.y); r[6] = f2bf(b.z); r[7] = f2bf(b.w);
  return r;
}

// Kernel 0: BT[l*E+k] = bf16(pc_Wp[k][l]);  w2[l] = W[l,:] . a2
__global__ void prep0(const float* __restrict__ W, const float* __restrict__ pc_W,
                      const float* __restrict__ a_W, short* __restrict__ BT,
                      float* __restrict__ w2){
  int l = blockIdx.x, t = threadIdx.x;
  BT[l*E + t] = f2bf(pc_W[(E + t)*E + l]);
  __shared__ float red[E];
  red[t] = W[l*E + t] * a_W[E + t];
  __syncthreads();
  for (int s = 64; s > 0; s >>= 1){ if (t < s) red[t] += red[t+s]; __syncthreads(); }
  if (t == 0) w2[l] = red[0];
}

// Kernel 1: per j: wf = embs[j]@W ; bias[j] = wf@pc_Wc + pc_b ; u[j] = wf . a1
__global__ void prep1(const float* __restrict__ embs, const float* __restrict__ W,
                      const float* __restrict__ pc_W, const float* __restrict__ pc_b,
                      const float* __restrict__ a_W,
                      float* __restrict__ bias, float* __restrict__ u){
  int j = blockIdx.x, t = threadIdx.x;
  __shared__ float se[E], swf[E], red[E];
  se[t] = embs[j*E + t];
  __syncthreads();
  float acc = 0.f;
  #pragma unroll 8
  for (int k = 0; k < E; k++) acc += se[k] * W[k*E + t];
  swf[t] = acc;
  __syncthreads();
  float ct = 0.f;
  #pragma unroll 8
  for (int k = 0; k < E; k++) ct += swf[k] * pc_W[k*E + t];
  bias[j*E + t] = ct + pc_b[t];
  red[t] = swf[t] * a_W[t];
  __syncthreads();
  for (int s = 64; s > 0; s >>= 1){ if (t < s) red[t] += red[t+s]; __syncthreads(); }
  if (t == 0) u[j] = red[0];
}

// Kernel 2: block = (j-group of JB, i-tile of 128). Software-pipelined over j:
// prefetch A(j+1) raw fp32 into regs while MFMA+epilogue on A(j). B staged once.
__global__ __launch_bounds__(256, 2)
void main_gemm(const float* __restrict__ pde, const short* __restrict__ BT,
               const float* __restrict__ bias, const float* __restrict__ u,
               const float* __restrict__ w2, const float* __restrict__ a_b,
               float* __restrict__ logits){
  __shared__ short sB[E*AST];          // ~34 KB
  __shared__ float sBias[JB][E];       // 4 KB
  __shared__ float sW2[E], sU[128];
  const int t = threadIdx.x;
  const int jg = blockIdx.x, it = blockIdx.y;
  const int j0 = jg * JB, i0 = it * 128;

  // stage B (bf16, 128x128) into padded LDS: row l holds k=0..127 contiguous
  {
    int rl = t >> 4;
    int kk = (t & 15) * 8;
    #pragma unroll
    for (int p = 0; p < 8; p++){
      int l = p*16 + rl;
      *(uint4*)(&sB[l*AST + kk]) = *(const uint4*)(&BT[l*E + kk]);
    }
  }
  // stage bias for all JB j's
  #pragma unroll
  for (int p = 0; p < JB*E/256; p++){
    int idx = p*256 + t;
    sBias[idx >> 7][idx & 127] = bias[(size_t)(j0 + (idx >> 7))*E + (idx & 127)];
  }
  if (t < 128){ sW2[t] = w2[t]; sU[t] = u[i0 + t]; }

  const int lane = t & 63;
  const int w = t >> 6;            // wave 0..3, rows [w*32, w*32+32)
  const int n = lane & 15;
  const int q = lane >> 4;
  const int rw = w * 32;

  // per-lane row base pointers (include q*8 k-offset), at j0
  const float* rp0 = pde + ((size_t)(i0 + rw + n)      * N + j0) * E + q*8;
  const float* rp1 = pde + ((size_t)(i0 + rw + 16 + n) * N + j0) * E + q*8;

  float4 raw[2][4][2];
  #pragma unroll
  for (int ks = 0; ks < 4; ks++){
    raw[0][ks][0] = *(const float4*)(rp0 + ks*32);
    raw[0][ks][1] = *(const float4*)(rp0 + ks*32 + 4);
    raw[1][ks][0] = *(const float4*)(rp1 + ks*32);
    raw[1][ks][1] = *(const float4*)(rp1 + ks*32 + 4);
  }

  __syncthreads();

  const float ab = a_b[0];

  #pragma unroll 2
  for (int jj = 0; jj < JB; jj++){
    // convert raw(j) -> bf16 frags (forces waitcnt on prior loads)
    short8 frag[2][4];
    #pragma unroll
    for (int mt = 0; mt < 2; mt++)
      #pragma unroll
      for (int ks = 0; ks < 4; ks++)
        frag[mt][ks] = cvt2(raw[mt][ks][0], raw[mt][ks][1]);

    // issue prefetch for j+1 (overlaps MFMA + epilogue below)
    if (jj < JB-1){
      int off = (jj+1) * E;
      #pragma unroll
      for (int ks = 0; ks < 4; ks++){
        raw[0][ks][0] = *(const float4*)(rp0 + off + ks*32);
        raw[0][ks][1] = *(const float4*)(rp0 + off + ks*32 + 4);
        raw[1][ks][0] = *(const float4*)(rp1 + off + ks*32);
        raw[1][ks][1] = *(const float4*)(rp1 + off + ks*32 + 4);
      }
    }

    float4v acc[2][8];
    #pragma unroll
    for (int mt = 0; mt < 2; mt++)
      #pragma unroll
      for (int ct = 0; ct < 8; ct++)
        acc[mt][ct] = (float4v){0.f, 0.f, 0.f, 0.f};

    #pragma unroll
    for (int ks = 0; ks < 4; ks++){
      int ko = ks*32 + q*8;
      #pragma unroll
      for (int ct = 0; ct < 8; ct++){
        short8 b = *(const short8*)(&sB[(ct*16 + n)*AST + ko]);
        acc[0][ct] = __builtin_amdgcn_mfma_f32_16x16x32_bf16(frag[0][ks], b, acc[0][ct], 0, 0, 0);
        acc[1][ct] = __builtin_amdgcn_mfma_f32_16x16x32_bf16(frag[1][ks], b, acc[1][ct], 0, 0, 0);
      }
    }

    // epilogue: y = lrelu(acc + bias[l]); s = sum_l y*w2[l]; logit = lrelu(u[i]+s+a_b)
    #pragma unroll
    for (int mt = 0; mt < 2; mt++){
      #pragma unroll
      for (int r = 0; r < 4; r++){
        float s = 0.f;
        #pragma unroll
        for (int ct = 0; ct < 8; ct++){
          int l = ct*16 + n;
          float y = acc[mt][ct][r] + sBias[jj][l];
          y = (y >= 0.f) ? y : NEG * y;
          s += y * sW2[l];
        }
        s += __shfl_xor(s, 1, 64);
        s += __shfl_xor(s, 2, 64);
        s += __shfl_xor(s, 4, 64);
        s += __shfl_xor(s, 8, 64);
        if (n == 0){
          int m = rw + mt*16 + q*4 + r;
          float lg = sU[m] + s + ab;
          lg = (lg >= 0.f) ? lg : NEG * lg;
          logits[(size_t)(i0 + m) * N + j0 + jj] = lg;
        }
      }
    }
  }
}

// Kernel 3: per output row i: mask+softmax over j (row-coalesced), nbc = attn@embs, concat
__global__ __launch_bounds__(256)
void softmax_nbc(const float* __restrict__ logits, const int* __restrict__ adj,
                 const float* __restrict__ embs, float* __restrict__ out){
  __shared__ float sAttn[N];
  __shared__ float wred[4];
  __shared__ float red[256];
  int i = blockIdx.x, t = threadIdx.x;
  int lane = t & 63, wv = t >> 6;
  float mymax = -__builtin_inff();
  #pragma unroll
  for (int p = 0; p < 4; p++){
    int j = p*256 + t;
    float v = logits[(size_t)i*N + j];
    v = (adj[(size_t)i*N + j] == 1) ? v : -__builtin_inff();
    sAttn[j] = v;
    mymax = fmaxf(mymax, v);
  }
  #pragma unroll
  for (int o = 32; o > 0; o >>= 1) mymax = fmaxf(mymax, __shfl_xor(mymax, o, 64));
  if (lane == 0) wred[wv] = mymax;
  __syncthreads();
  float M = fmaxf(fmaxf(wred[0], wred[1]), fmaxf(wred[2], wred[3]));
  __syncthreads();
  float mysum = 0.f;
  #pragma unroll
  for (int p = 0; p < 4; p++){
    int j = p*256 + t;
    float e = __expf(sAttn[j] - M);
    sAttn[j] = e;
    mysum += e;
  }
  #pragma unroll
  for (int o = 32; o > 0; o >>= 1) mysum += __shfl_xor(mysum, o, 64);
  if (lane == 0) wred[wv] = mysum;
  __syncthreads();
  float inv = 1.0f / (wred[0] + wred[1] + wred[2] + wred[3]);
  __syncthreads();
  int l = t & 127, jh = t >> 7;
  float acc = 0.f;
  #pragma unroll 8
  for (int jj = 0; jj < 512; jj++){
    int j = jh*512 + jj;
    acc += sAttn[j] * embs[j*E + l];
  }
  red[t] = acc; __syncthreads();
  if (t < 128){
    out[(size_t)i*2*E + t]     = embs[i*E + t];
    out[(size_t)i*2*E + E + t] = (red[t] + red[t+128]) * inv;
  }
}

extern "C" void kernel_launch(void* const* d_in, const int* in_sizes, int n_in,
                              void* d_out, int out_size, void* d_ws, size_t ws_size,
                              hipStream_t stream) {
  const float* embs = (const float*)d_in[0];
  const int*   adj  = (const int*)d_in[1];
  const float* pde  = (const float*)d_in[2];
  const float* W    = (const float*)d_in[3];
  const float* pc_W = (const float*)d_in[4];
  const float* pc_b = (const float*)d_in[5];
  const float* a_W  = (const float*)d_in[6];
  const float* a_b  = (const float*)d_in[7];
  float* out = (float*)d_out;

  float* ws      = (float*)d_ws;
  float* logits  = ws;                          // N*N floats (4 MB), row-major
  float* bias    = ws + (size_t)N*N;            // N*E floats
  float* u       = bias + (size_t)N*E;          // N floats
  float* w2      = u + N;                       // E floats
  short* BT      = (short*)(w2 + E);            // E*E bf16 (16B-aligned offset)

  prep0<<<dim3(E), dim3(E), 0, stream>>>(W, pc_W, a_W, BT, w2);
  prep1<<<dim3(N), dim3(E), 0, stream>>>(embs, W, pc_W, pc_b, a_W, bias, u);
  main_gemm<<<dim3(N/JB, N/128), dim3(256), 0, stream>>>(pde, BT, bias, u, w2, a_b, logits);
  softmax_nbc<<<dim3(N), dim3(256), 0, stream>>>(logits, adj, embs, out);
}

// Round 4
// 744.183 us; speedup vs baseline: 1.1592x; 1.1592x over previous
//
#include <hip/hip_runtime.h>
#include <hip/hip_bf16.h>

#define N 1024
#define E 128
#define NEG 0.2f
#define AST 136  // padded LDS stride (shorts) for B tile

typedef __attribute__((ext_vector_type(8))) short short8;
typedef __attribute__((ext_vector_type(4))) float float4v;

__device__ __forceinline__ short f2bf(float x){
  unsigned u = __float_as_uint(x);
  u += 0x7fffu + ((u >> 16) & 1u);   // round-to-nearest-even
  return (short)(u >> 16);
}

__device__ __forceinline__ short8 cvt2(float4 a, float4 b){
  short8 r;
  r[0] = f2bf(a.x); r[1] = f2bf(a.y); r[2] = f2bf(a.z); r[3] = f2bf(a.w);
  r[4] = f2bf(b.x); r[5] = f2bf(b.y); r[6] = f2bf(b.z); r[7] = f2bf(b.w);
  return r;
}

// Merged prep: blocks [0,E) do prep0 (l=b); blocks [E, E+N) do prep1 (j=b-E).
__global__ void prep(const float* __restrict__ embs, const float* __restrict__ W,
                     const float* __restrict__ pc_W, const float* __restrict__ pc_b,
                     const float* __restrict__ a_W,
                     short* __restrict__ BT, float* __restrict__ w2,
                     float* __restrict__ bias, float* __restrict__ u){
  int b = blockIdx.x, t = threadIdx.x;
  __shared__ float se[E], swf[E], red[E];
  if (b < E){
    int l = b;
    BT[l*E + t] = f2bf(pc_W[(E + t)*E + l]);
    red[t] = W[l*E + t] * a_W[E + t];
    __syncthreads();
    for (int s = 64; s > 0; s >>= 1){ if (t < s) red[t] += red[t+s]; __syncthreads(); }
    if (t == 0) w2[l] = red[0];
  } else {
    int j = b - E;
    se[t] = embs[j*E + t];
    __syncthreads();
    float acc = 0.f;
    #pragma unroll 8
    for (int k = 0; k < E; k++) acc += se[k] * W[k*E + t];
    swf[t] = acc;
    __syncthreads();
    float ct = 0.f;
    #pragma unroll 8
    for (int k = 0; k < E; k++) ct += swf[k] * pc_W[k*E + t];
    bias[j*E + t] = ct + pc_b[t];
    red[t] = swf[t] * a_W[t];
    __syncthreads();
    for (int s = 64; s > 0; s >>= 1){ if (t < s) red[t] += red[t+s]; __syncthreads(); }
    if (t == 0) u[j] = red[0];
  }
}

// Kernel 2: block = (fixed j, i-tile of 128). One-shot, low-VGPR per-ct accumulation.
// logits[i,j] = lrelu(u[i] + sum_l lrelu(pde[i,j,:].Bp[:,l] + bias[j,l])*w2[l] + a_b)
__global__ __launch_bounds__(256, 4)
void main_gemm(const float* __restrict__ pde, const short* __restrict__ BT,
               const float* __restrict__ bias, const float* __restrict__ u,
               const float* __restrict__ w2, const float* __restrict__ a_b,
               float* __restrict__ logits){
  __shared__ short sB[E*AST];          // ~34 KB
  __shared__ float sBias[E], sW2[E], sU[128];
  const int t = threadIdx.x;
  const int j = blockIdx.x, it = blockIdx.y;
  const int i0 = it * 128;

  // stage B (bf16, 128x128) into padded LDS
  {
    int rl = t >> 4;
    int kk = (t & 15) * 8;
    #pragma unroll
    for (int p = 0; p < 8; p++){
      int l = p*16 + rl;
      *(uint4*)(&sB[l*AST + kk]) = *(const uint4*)(&BT[l*E + kk]);
    }
  }
  if (t < 128){
    sBias[t] = bias[j*E + t];
    sW2[t]   = w2[t];
    sU[t]    = u[i0 + t];
  }

  const int lane = t & 63;
  const int w = t >> 6;            // wave 0..3, rows [w*32, w*32+32)
  const int n = lane & 15;
  const int q = lane >> 4;
  const int rw = w * 32;

  // A fragments: direct global->reg, fp32->bf16.  A[m=lane&15][k=q*8+jj]
  const float* rp0 = pde + ((size_t)(i0 + rw + n)      * N + j) * E + q*8;
  const float* rp1 = pde + ((size_t)(i0 + rw + 16 + n) * N + j) * E + q*8;

  short8 frag[2][4];
  #pragma unroll
  for (int ks = 0; ks < 4; ks++){
    float4 a0 = *(const float4*)(rp0 + ks*32);
    float4 a1 = *(const float4*)(rp0 + ks*32 + 4);
    float4 b0 = *(const float4*)(rp1 + ks*32);
    float4 b1 = *(const float4*)(rp1 + ks*32 + 4);
    frag[0][ks] = cvt2(a0, a1);
    frag[1][ks] = cvt2(b0, b1);
  }

  __syncthreads();

  const float ab = a_b[0];
  float s0[4] = {0.f, 0.f, 0.f, 0.f};   // partial logit sums, mt=0, r=0..3
  float s1[4] = {0.f, 0.f, 0.f, 0.f};   // mt=1

  #pragma unroll
  for (int ct = 0; ct < 8; ct++){
    const int l = ct*16 + n;
    short8 b[4];
    #pragma unroll
    for (int ks = 0; ks < 4; ks++)
      b[ks] = *(const short8*)(&sB[l*AST + ks*32 + q*8]);

    float4v acc0 = (float4v){0.f,0.f,0.f,0.f};
    float4v acc1 = (float4v){0.f,0.f,0.f,0.f};
    #pragma unroll
    for (int ks = 0; ks < 4; ks++){
      acc0 = __builtin_amdgcn_mfma_f32_16x16x32_bf16(frag[0][ks], b[ks], acc0, 0, 0, 0);
      acc1 = __builtin_amdgcn_mfma_f32_16x16x32_bf16(frag[1][ks], b[ks], acc1, 0, 0, 0);
    }

    const float bl = sBias[l], wl = sW2[l];
    #pragma unroll
    for (int r = 0; r < 4; r++){
      float y0 = acc0[r] + bl; y0 = (y0 >= 0.f) ? y0 : NEG * y0;
      float y1 = acc1[r] + bl; y1 = (y1 >= 0.f) ? y1 : NEG * y1;
      s0[r] += y0 * wl;
      s1[r] += y1 * wl;
    }
  }

  // reduce over n (16 lanes), write logits
  #pragma unroll
  for (int r = 0; r < 4; r++){
    float a = s0[r], c = s1[r];
    a += __shfl_xor(a, 1, 64); c += __shfl_xor(c, 1, 64);
    a += __shfl_xor(a, 2, 64); c += __shfl_xor(c, 2, 64);
    a += __shfl_xor(a, 4, 64); c += __shfl_xor(c, 4, 64);
    a += __shfl_xor(a, 8, 64); c += __shfl_xor(c, 8, 64);
    if (n == 0){
      int m0 = rw + q*4 + r;
      float lg = sU[m0] + a + ab;
      lg = (lg >= 0.f) ? lg : NEG * lg;
      logits[(size_t)(i0 + m0) * N + j] = lg;
      int m1 = rw + 16 + q*4 + r;
      float lh = sU[m1] + c + ab;
      lh = (lh >= 0.f) ? lh : NEG * lh;
      logits[(size_t)(i0 + m1) * N + j] = lh;
    }
  }
}

// Kernel 3: per output row i: mask+softmax over j (float4 row loads), nbc = attn@embs, concat
__global__ __launch_bounds__(256)
void softmax_nbc(const float* __restrict__ logits, const int* __restrict__ adj,
                 const float* __restrict__ embs, float* __restrict__ out){
  __shared__ float sAttn[N];
  __shared__ float wred[4];
  __shared__ float red[256];
  int i = blockIdx.x, t = threadIdx.x;
  int lane = t & 63, wv = t >> 6;

  float4 lv = *(const float4*)(logits + (size_t)i*N + 4*t);
  int4   av = *(const int4*)  (adj    + (size_t)i*N + 4*t);
  float v0 = (av.x == 1) ? lv.x : -__builtin_inff();
  float v1 = (av.y == 1) ? lv.y : -__builtin_inff();
  float v2 = (av.z == 1) ? lv.z : -__builtin_inff();
  float v3 = (av.w == 1) ? lv.w : -__builtin_inff();
  float mymax = fmaxf(fmaxf(v0, v1), fmaxf(v2, v3));
  #pragma unroll
  for (int o = 32; o > 0; o >>= 1) mymax = fmaxf(mymax, __shfl_xor(mymax, o, 64));
  if (lane == 0) wred[wv] = mymax;
  __syncthreads();
  float M = fmaxf(fmaxf(wred[0], wred[1]), fmaxf(wred[2], wred[3]));
  __syncthreads();

  float e0 = __expf(v0 - M), e1 = __expf(v1 - M), e2 = __expf(v2 - M), e3 = __expf(v3 - M);
  *(float4*)(&sAttn[4*t]) = (float4){e0, e1, e2, e3};
  float mysum = (e0 + e1) + (e2 + e3);
  #pragma unroll
  for (int o = 32; o > 0; o >>= 1) mysum += __shfl_xor(mysum, o, 64);
  if (lane == 0) wred[wv] = mysum;
  __syncthreads();
  float inv = 1.0f / (wred[0] + wred[1] + wred[2] + wred[3]);

  int l = t & 127, jh = t >> 7;
  float acc = 0.f;
  #pragma unroll 8
  for (int jj = 0; jj < 512; jj++){
    int j = jh*512 + jj;
    acc += sAttn[j] * embs[j*E + l];
  }
  red[t] = acc; __syncthreads();
  if (t < 128){
    out[(size_t)i*2*E + t]     = embs[i*E + t];
    out[(size_t)i*2*E + E + t] = (red[t] + red[t+128]) * inv;
  }
}

extern "C" void kernel_launch(void* const* d_in, const int* in_sizes, int n_in,
                              void* d_out, int out_size, void* d_ws, size_t ws_size,
                              hipStream_t stream) {
  const float* embs = (const float*)d_in[0];
  const int*   adj  = (const int*)d_in[1];
  const float* pde  = (const float*)d_in[2];
  const float* W    = (const float*)d_in[3];
  const float* pc_W = (const float*)d_in[4];
  const float* pc_b = (const float*)d_in[5];
  const float* a_W  = (const float*)d_in[6];
  const float* a_b  = (const float*)d_in[7];
  float* out = (float*)d_out;

  float* ws      = (float*)d_ws;
  float* logits  = ws;                          // N*N floats (4 MB), row-major
  float* bias    = ws + (size_t)N*N;            // N*E floats
  float* u       = bias + (size_t)N*E;          // N floats
  float* w2      = u + N;                       // E floats
  short* BT      = (short*)(w2 + E);            // E*E bf16 (16B-aligned offset)

  prep<<<dim3(E + N), dim3(E), 0, stream>>>(embs, W, pc_W, pc_b, a_W, BT, w2, bias, u);
  main_gemm<<<dim3(N, N/128), dim3(256), 0, stream>>>(pde, BT, bias, u, w2, a_b, logits);
  softmax_nbc<<<dim3(N), dim3(256), 0, stream>>>(logits, adj, embs, out);
}